// Round 9
// baseline (228.310 us; speedup 1.0000x reference)
//
#include <hip/hip_runtime.h>
#include <math.h>

#define BB 8192
#define DIN 1024
#define DZ 256
#define DH 256
#define DT 16
#define DREC 256

// d_out layout (floats): I_hat, z, h, z_hat, spatial, temporal, energy
#define OFF_IHAT 0
#define OFF_Z    (BB * DIN)
#define OFF_H    (OFF_Z + BB * DZ)
#define OFF_ZHAT (OFF_H + BB * DH)
#define OFF_SCAL (OFF_ZHAT + BB * DZ)

// ---- workspace layout (u16 element offsets) -------------------------------
// (h/zm1 bf16 regions retained in layout but no longer used)
#define WS_HBF   0
#define WS_ZM1   2097152
#define WS_W     4194304
#define W_PM  (WS_W + 0)
#define W_PL  (W_PM + 262144)
#define W_Z2H (W_PL + 262144)
#define W_H2H (W_Z2H + 65536)
#define W_PRM (W_H2H + 65536)
#define W_PRL (W_PRM + 65536)
#define W_I2T (W_PRL + 65536)      // pre-scaled by 0.1
#define W_VIP (W_I2T + 16384)      // stored as -relu(W)
#define W_R1  (W_VIP + 4096)
#define W_R2  (W_R1 + 65536)
#define WS_ENDW  (W_R2 + 262144)
#define WS_SIGMA WS_ENDW
#define WS_ZBF   (WS_SIGMA + 2097152)
#define WS_R1BF  (WS_ZBF + 2097152)

typedef unsigned short u16;
typedef __attribute__((ext_vector_type(8))) unsigned short u16x8;
typedef __attribute__((ext_vector_type(8))) __bf16 bf16x8;
typedef __attribute__((ext_vector_type(4))) float f32x4;

#define MFMA __builtin_amdgcn_mfma_f32_16x16x32_bf16

__device__ inline u16 f2bf(float f) {
  unsigned u = __builtin_bit_cast(unsigned, f);
  u += 0x7fff + ((u >> 16) & 1);
  return (u16)(u >> 16);
}
__device__ inline float softplus_stable(float y) {  // log(1+e^y)
  return (y > 20.f) ? y : log1pf(expf(y));
}
__device__ inline bf16x8 gf(const u16* p) {
  return __builtin_bit_cast(bf16x8, *(const u16x8*)p);
}
__device__ inline f32x4 fzero() { return (f32x4){0.f, 0.f, 0.f, 0.f}; }

__device__ inline float block_sum512(float v, float* rbuf) {
#pragma unroll
  for (int off = 32; off > 0; off >>= 1) v += __shfl_down(v, off, 64);
  __syncthreads();
  if ((threadIdx.x & 63) == 0) rbuf[threadIdx.x >> 6] = v;
  __syncthreads();
  float s = 0.f;
#pragma unroll
  for (int i = 0; i < 8; ++i) s += rbuf[i];
  return s;
}

// 128-k-wide panels (512 threads / 8 waves): row = 128 u16 = 256 B;
// one global_load_lds instr covers 4 rows (64 lanes x 16 B).
// LDS[r][c] = G[r][c ^ (r&7)] (chunk involution, c in 0..15) -> conflict-light.
__device__ inline void stg64x128(u16* tile, const u16* __restrict__ g,
                                 int row0, int ldk, int k0) {
  const int lane = threadIdx.x & 63, w = threadIdx.x >> 6;
#pragma unroll
  for (int i = 0; i < 2; ++i) {
    int rb = (w * 2 + i) * 4;              // 8 waves x 2 x 4 rows = 64
    int r = rb + (lane >> 4);
    int d = lane & 15;
    int s = d ^ (r & 7);
    const u16* src = g + (size_t)(row0 + r) * ldk + k0 + s * 8;
    u16* dst = tile + rb * 128;
    __builtin_amdgcn_global_load_lds(
        (const __attribute__((address_space(1))) unsigned int*)(const void*)src,
        (__attribute__((address_space(3))) unsigned int*)(void*)dst, 16, 0, 0);
  }
}
__device__ inline void stg16x128(u16* tile, const u16* __restrict__ g,
                                 int ldk, int k0) {
  const int lane = threadIdx.x & 63, w = threadIdx.x >> 6;
  if (w < 4) {
    int rb = w * 4;                        // 4 waves x 4 rows = 16
    int r = rb + (lane >> 4);
    int d = lane & 15;
    int s = d ^ (r & 7);
    const u16* src = g + (size_t)r * ldk + k0 + s * 8;
    u16* dst = tile + rb * 128;
    __builtin_amdgcn_global_load_lds(
        (const __attribute__((address_space(1))) unsigned int*)(const void*)src,
        (__attribute__((address_space(3))) unsigned int*)(void*)dst, 16, 0, 0);
  }
}
__device__ inline bf16x8 rd128(const u16* tile, int r, int j) {
  return gf(tile + r * 128 + ((j ^ (r & 7)) * 8));
}

// per-phase helpers (all static indexing)
// bf16-source A fragments (sigma pass)
__device__ inline void lda4(bf16x8 (&ar)[4], const u16* base, int kwin,
                            int fq) {
#pragma unroll
  for (int kk = 0; kk < 4; ++kk) ar[kk] = gf(base + kwin + kk * 32 + fq * 8);
}
// fp32-source A fragments with in-register bf16 conversion (fused k_cvt).
// f2bf is bit-identical to the old k_cvt path -> numerics unchanged.
__device__ inline void lda4f(bf16x8 (&ar)[4], const float* __restrict__ base,
                             int kwin, int fq) {
#pragma unroll
  for (int kk = 0; kk < 4; ++kk) {
    const float* p = base + kwin + kk * 32 + fq * 8;
    float4 v0 = ((const float4*)p)[0];
    float4 v1 = ((const float4*)p)[1];
    float vals[8] = {v0.x, v0.y, v0.z, v0.w, v1.x, v1.y, v1.z, v1.w};
    u16x8 o;
#pragma unroll
    for (int j = 0; j < 8; ++j) o[j] = f2bf(vals[j]);
    ar[kk] = __builtin_bit_cast(bf16x8, o);
  }
}
// k_post: mu/sg (4 cols) + theta
__device__ inline void cmpMain(const u16* buf, bf16x8 (&ar)[4], f32x4 (&mu)[4],
                               f32x4 (&sg)[4], f32x4& tt, int frow, int fq) {
#pragma unroll
  for (int kk = 0; kk < 4; ++kk) {
    int j = kk * 4 + fq;
#pragma unroll
    for (int n = 0; n < 4; ++n) {
      mu[n] = MFMA(ar[kk], rd128(buf, n * 16 + frow, j), mu[n], 0, 0, 0);
      sg[n] = MFMA(ar[kk], rd128(buf + 8192, n * 16 + frow, j), sg[n], 0, 0, 0);
    }
    tt = MFMA(ar[kk], rd128(buf + 16384, frow, j), tt, 0, 0, 0);
  }
}
__device__ inline void cmpSig(const u16* buf, bf16x8 (&ar)[4], f32x4& tt,
                              int frow, int fq) {
#pragma unroll
  for (int kk = 0; kk < 4; ++kk)
    tt = MFMA(ar[kk], rd128(buf + 16384, frow, kk * 4 + fq), tt, 0, 0, 0);
}
// k_hp: 3 mats (pass1) / 1 mat (pass2, also used by k_rec1/k_rec2)
__device__ inline void hpCmp3(const u16* buf, bf16x8 (&ar)[4], f32x4 (&ah)[4],
                              f32x4 (&am)[4], f32x4 (&as_)[4], int frow,
                              int fq) {
#pragma unroll
  for (int kk = 0; kk < 4; ++kk) {
    int j = kk * 4 + fq;
#pragma unroll
    for (int n = 0; n < 4; ++n) {
      ah[n]  = MFMA(ar[kk], rd128(buf, n * 16 + frow, j), ah[n], 0, 0, 0);
      am[n]  = MFMA(ar[kk], rd128(buf + 8192, n * 16 + frow, j), am[n], 0, 0, 0);
      as_[n] = MFMA(ar[kk], rd128(buf + 16384, n * 16 + frow, j), as_[n], 0, 0, 0);
    }
  }
}
__device__ inline void hpCmp1(const u16* buf, bf16x8 (&ar)[4], f32x4 (&ah)[4],
                              int frow, int fq) {
#pragma unroll
  for (int kk = 0; kk < 4; ++kk) {
    int j = kk * 4 + fq;
#pragma unroll
    for (int n = 0; n < 4; ++n)
      ah[n] = MFMA(ar[kk], rd128(buf, n * 16 + frow, j), ah[n], 0, 0, 0);
  }
}

// ---------------------------------------------------------------------------
// k_cvt: fp32 -> bf16 for WEIGHTS only (I/h/zm1 conversion fused into the
// GEMM kernels' A-loads).  1.13M elems.
// ---------------------------------------------------------------------------
__global__ __launch_bounds__(256) void k_cvt(
    const float* __restrict__ Wpm, const float* __restrict__ Wpl,
    const float* __restrict__ Wz2h, const float* __restrict__ Wh2h,
    const float* __restrict__ Wprm, const float* __restrict__ Wprl,
    const float* __restrict__ Wi2t, const float* __restrict__ Wv,
    const float* __restrict__ Wr1, const float* __restrict__ Wr2,
    u16* __restrict__ dstW) {
  const int T1 = 262144, T2 = 524288, T3 = 589824, T4 = 655360, T5 = 720896,
            T6 = 786432, T7 = 802816, T8 = 806912, T9 = 872448, T10 = 1134592;
  int nchunk = T10 / 8;
  for (int c = blockIdx.x * 256 + threadIdx.x; c < nchunk;
       c += gridDim.x * 256) {
    int f = c * 8;
    const float* src;
    float scale = 1.f;
    bool nrelu = false;
    if (f < T1)       src = Wpm + f;
    else if (f < T2)  src = Wpl + (f - T1);
    else if (f < T3)  src = Wz2h + (f - T2);
    else if (f < T4)  src = Wh2h + (f - T3);
    else if (f < T5)  src = Wprm + (f - T4);
    else if (f < T6)  src = Wprl + (f - T5);
    else if (f < T7)  { src = Wi2t + (f - T6); scale = 0.1f; }
    else if (f < T8)  { src = Wv + (f - T7);   nrelu = true; }
    else if (f < T9)  src = Wr1 + (f - T8);
    else              src = Wr2 + (f - T9);
    float4 v0 = *(const float4*)(src);
    float4 v1 = *(const float4*)(src + 4);
    float vals[8] = {v0.x, v0.y, v0.z, v0.w, v1.x, v1.y, v1.z, v1.w};
    u16x8 o;
#pragma unroll
    for (int j = 0; j < 8; ++j) {
      float x = vals[j];
      x = nrelu ? -fmaxf(x, 0.f) : x * scale;
      o[j] = f2bf(x);
    }
    *(u16x8*)(dstW + f) = o;
  }
}

// ---------------------------------------------------------------------------
// k_hp: 256 blocks (1/CU), 512 threads (8 waves), 128x64 tile; wave = 16
// rows.  A (h, zm1) = fp32 direct global->VGPR with fused bf16 cvt.
// B = 2 x 48 KB LDS K=128 panels.  4 phases + two-half-pass epilogue.
// ---------------------------------------------------------------------------
__global__ __launch_bounds__(512, 2) void k_hp(
    const float* __restrict__ h_m_1, const float* __restrict__ z_m_1,
    const u16* __restrict__ Wh2h, const u16* __restrict__ Wprm,
    const u16* __restrict__ Wprl, const u16* __restrict__ Wz2h,
    const float* __restrict__ eps_zhat, float* __restrict__ h_out,
    float* __restrict__ zhat_out, u16* __restrict__ sigma_bf) {
  __shared__ __align__(16) u16 smem[2 * 24576];  // 96 KB panel ring
  const int tid = threadIdx.x, lane = tid & 63, w = tid >> 6;  // w: 0..7
  const int frow = lane & 15, fq = lane >> 4;
  int row0, col0;
  {
    int xcd = blockIdx.x & 7, t = blockIdx.x >> 3;
    col0 = (t & 3) * 64;
    row0 = ((t >> 2) * 8 + xcd) * 128;
  }
  u16* b0 = smem;
  u16* b1 = smem + 24576;

  f32x4 ah[4], am[4], as_[4];
#pragma unroll
  for (int n = 0; n < 4; ++n) { ah[n] = fzero(); am[n] = fzero(); as_[n] = fzero(); }

  const float* Ah = h_m_1 + (size_t)(row0 + w * 16 + frow) * DH;
  const float* Az = z_m_1 + (size_t)(row0 + w * 16 + frow) * DZ;
  bf16x8 arA[4], arB[4];

  // prologue: phase 0 (A=h, K 0..127) into b0
  stg64x128(b0, Wh2h, col0, DH, 0);
  stg64x128(b0 + 8192, Wprm, col0, DH, 0);
  stg64x128(b0 + 16384, Wprl, col0, DH, 0);
  lda4f(arA, Ah, 0, fq);
  // phase 0 computes b0; prefetch phase 1 (A=h, K 128..255) into b1
  __syncthreads();
  stg64x128(b1, Wh2h, col0, DH, 128);
  stg64x128(b1 + 8192, Wprm, col0, DH, 128);
  stg64x128(b1 + 16384, Wprl, col0, DH, 128);
  lda4f(arB, Ah, 128, fq);
  hpCmp3(b0, arA, ah, am, as_, frow, fq);
  // phase 1 computes b1; prefetch phase 2 (A=zm1, Wz2h K 0..127) into b0
  __syncthreads();
  stg64x128(b0, Wz2h, col0, DZ, 0);
  lda4f(arA, Az, 0, fq);
  hpCmp3(b1, arB, ah, am, as_, frow, fq);
  // phase 2 computes b0; prefetch phase 3 (Wz2h K 128..255) into b1
  __syncthreads();
  stg64x128(b1, Wz2h, col0, DZ, 128);
  lda4f(arB, Az, 128, fq);
  hpCmp1(b0, arA, ah, frow, fq);
  // phase 3 computes b1
  __syncthreads();
  hpCmp1(b1, arB, ah, frow, fq);

  // epilogue: two 64-row half-passes; scratch overlaid on dead staging LDS
  float* ht = (float*)smem;              // 64 x 66
  float* mt = (float*)(smem + 8448);     // 64 x 66
  float* st = (float*)(smem + 16896);    // 64 x 66
#pragma unroll 1
  for (int p = 0; p < 2; ++p) {
    __syncthreads();  // (p=0: also guards b1 reads done before overwrite)
    if ((w >> 2) == p) {
#pragma unroll
      for (int n = 0; n < 4; ++n)
#pragma unroll
        for (int r = 0; r < 4; ++r) {
          int lrl = (w & 3) * 16 + fq * 4 + r;
          int ln = n * 16 + frow;
          ht[lrl * 66 + ln] = fmaxf(ah[n][r], 0.f);
          mt[lrl * 66 + ln] = fmaxf(am[n][r], 0.f);
          st[lrl * 66 + ln] = softplus_stable(1.2f * as_[n][r]) * (1.f / 1.2f);
        }
    }
    __syncthreads();
    // linear writes: thread -> row tid>>3 (0..63), cols (tid&7)*8..+8
    int lr2 = tid >> 3, c0 = (tid & 7) * 8;
    int m2 = row0 + p * 64 + lr2;
    float h8[8], mu8[8], sg8[8];
#pragma unroll
    for (int j = 0; j < 8; ++j) {
      h8[j] = ht[lr2 * 66 + c0 + j];
      mu8[j] = mt[lr2 * 66 + c0 + j];
      sg8[j] = st[lr2 * 66 + c0 + j];
    }
    float* hp = h_out + (size_t)m2 * DH + col0 + c0;
    *(float4*)hp = make_float4(h8[0], h8[1], h8[2], h8[3]);
    *(float4*)(hp + 4) = make_float4(h8[4], h8[5], h8[6], h8[7]);
    const float* ep = eps_zhat + (size_t)m2 * DZ + col0 + c0;
    float4 e0 = ((const float4*)ep)[0], e1 = ((const float4*)ep)[1];
    float e8[8] = {e0.x, e0.y, e0.z, e0.w, e1.x, e1.y, e1.z, e1.w};
    float zh8[8];
    u16x8 sb;
#pragma unroll
    for (int j = 0; j < 8; ++j) {
      zh8[j] = mu8[j] + e8[j] * sg8[j];
      sb[j] = f2bf(sg8[j]);
    }
    float* zp = zhat_out + (size_t)m2 * DZ + col0 + c0;
    *(float4*)zp = make_float4(zh8[0], zh8[1], zh8[2], zh8[3]);
    *(float4*)(zp + 4) = make_float4(zh8[4], zh8[5], zh8[6], zh8[7]);
    *(u16x8*)(sigma_bf + (size_t)m2 * DZ + col0 + c0) = sb;
  }
}

// ---------------------------------------------------------------------------
// k_post: 256 blocks (1/CU), 512 threads (8 waves), 128 rows x 64 cols;
// wave = 16 rows x 64 cols.  A = fp32 I_t direct global->VGPR with fused
// bf16 cvt (ping-pong arA/arB).  B = 2 x 36 KB LDS K=128 panels
// (Wpm|Wpl|Wi2t), 10-phase ring (8 main + 2 sigma), ONE __syncthreads/phase.
// ---------------------------------------------------------------------------
__global__ __launch_bounds__(512, 2) void k_post(
    const float* __restrict__ I_t, const u16* __restrict__ Wpm,
    const u16* __restrict__ Wpl, const u16* __restrict__ Wi2t,
    const u16* __restrict__ Wv, const u16* __restrict__ sigma_bf,
    const float* __restrict__ theta_m_1, const float* __restrict__ W_t2z,
    const float* __restrict__ eps_z, const float* __restrict__ zhat,
    float* __restrict__ z_out, u16* __restrict__ z_bf,
    float* __restrict__ scal) {
  __shared__ __align__(16) u16 smem[2 * 18432];      // 72 KB panel ring
  __shared__ float thwt[128 * 17 + 64 * 17];         // th_s | wt_s
  __shared__ float rbuf[8];
  const int tid = threadIdx.x, lane = tid & 63, w = tid >> 6;  // w: 0..7
  const int frow = lane & 15, fq = lane >> 4;
  int row0, col0;
  {
    int xcd = blockIdx.x & 7, t = blockIdx.x >> 3;
    col0 = (t & 3) * 64;
    row0 = ((t >> 2) * 8 + xcd) * 128;
  }
  u16* b0 = smem;
  u16* b1 = smem + 18432;

  f32x4 mu[4], sg[4], tt = fzero();
#pragma unroll
  for (int i = 0; i < 4; ++i) { mu[i] = fzero(); sg[i] = fzero(); }

  const float* Abase = I_t + (size_t)(row0 + w * 16 + frow) * DIN;
  const u16* Sbase = sigma_bf + (size_t)(row0 + w * 16 + frow) * DZ;
  bf16x8 arA[4], arB[4];

#define STGM(buf, k0)                           \
  stg64x128(buf, Wpm, col0, DIN, k0);           \
  stg64x128((buf) + 8192, Wpl, col0, DIN, k0);  \
  stg16x128((buf) + 16384, Wi2t, DIN, k0)

  // prologue: phase 0 into b0
  STGM(b0, 0);
  lda4f(arA, Abase, 0, fq);
  // phases 0..7: main GEMMs (K=1024); phase t computes b[t&1]
  __syncthreads(); STGM(b1, 128); lda4f(arB, Abase, 128, fq);
  cmpMain(b0, arA, mu, sg, tt, frow, fq);
  __syncthreads(); STGM(b0, 256); lda4f(arA, Abase, 256, fq);
  cmpMain(b1, arB, mu, sg, tt, frow, fq);
  __syncthreads(); STGM(b1, 384); lda4f(arB, Abase, 384, fq);
  cmpMain(b0, arA, mu, sg, tt, frow, fq);
  __syncthreads(); STGM(b0, 512); lda4f(arA, Abase, 512, fq);
  cmpMain(b1, arB, mu, sg, tt, frow, fq);
  __syncthreads(); STGM(b1, 640); lda4f(arB, Abase, 640, fq);
  cmpMain(b0, arA, mu, sg, tt, frow, fq);
  __syncthreads(); STGM(b0, 768); lda4f(arA, Abase, 768, fq);
  cmpMain(b1, arB, mu, sg, tt, frow, fq);
  __syncthreads(); STGM(b1, 896); lda4f(arB, Abase, 896, fq);
  cmpMain(b0, arA, mu, sg, tt, frow, fq);
  // phase 7 computes b1; prefetch sigma phase 8 (Wv k0=0 into b0.Bt)
  __syncthreads(); stg16x128(b0 + 16384, Wv, DZ, 0); lda4(arA, Sbase, 0, fq);
  cmpMain(b1, arB, mu, sg, tt, frow, fq);
  // phase 8: sigma K 0..127 from b0; prefetch Wv k0=128 into b1.Bt
  __syncthreads(); stg16x128(b1 + 16384, Wv, DZ, 128); lda4(arB, Sbase, 128, fq);
  cmpSig(b0, arA, tt, frow, fq);
  // phase 9: sigma K 128..255 from b1
  __syncthreads();
  cmpSig(b1, arB, tt, frow, fq);
#undef STGM

  __syncthreads();  // staging LDS now dead -> epilogue scratch
  float* mt   = (float*)smem;            // 128 x 66
  float* st   = (float*)(smem + 16896);  // 128 x 66
  float* th_s = thwt;                    // 128 x 17
  float* wt_s = thwt + 128 * 17;         // 64 x 17

  // theta finalize: each wave owns its 16 rows (no in-block redundancy)
#pragma unroll
  for (int r = 0; r < 4; ++r) {
    int lr = w * 16 + fq * 4 + r;
    float th = 0.5f * theta_m_1[(size_t)(row0 + lr) * DT + frow] + tt[r];
    th_s[lr * 17 + frow] = 0.002f * softplus_stable(0.5f * th);
  }
  for (int idx = tid; idx < 64 * 16; idx += 512) {
    int n = idx >> 4, j = idx & 15;
    wt_s[n * 17 + j] = 10.f * fmaxf(W_t2z[(col0 + n) * DT + j], 0.f);
  }
  // scattered mu/sig -> LDS tiles
#pragma unroll
  for (int n = 0; n < 4; ++n)
#pragma unroll
    for (int r = 0; r < 4; ++r) {
      int lr = w * 16 + fq * 4 + r;
      int ln = n * 16 + frow;
      mt[lr * 66 + ln] = fmaxf(mu[n][r], 0.f);
      st[lr * 66 + ln] = fmaxf(sg[n][r], 0.f);
    }
  __syncthreads();
  // linear phase: thread -> row tid>>2, cols (tid&3)*16..+16; z + losses
  float tsum = 0.f, esum = 0.f;
  {
    int lr2 = tid >> 2, c0 = (tid & 3) * 16;
    int m2 = row0 + lr2;
    float thv[16];
#pragma unroll
    for (int j = 0; j < 16; ++j) thv[j] = th_s[lr2 * 17 + j];
#pragma unroll
    for (int gb = 0; gb < 2; ++gb) {
      int c = c0 + gb * 8;
      float mu8[8], sg8[8];
#pragma unroll
      for (int j = 0; j < 8; ++j) {
        mu8[j] = mt[lr2 * 66 + c + j];
        sg8[j] = st[lr2 * 66 + c + j];
      }
      const float* ep = eps_z + (size_t)m2 * DZ + col0 + c;
      float4 e0 = ((const float4*)ep)[0], e1 = ((const float4*)ep)[1];
      float e8[8] = {e0.x, e0.y, e0.z, e0.w, e1.x, e1.y, e1.z, e1.w};
      float z8[8];
#pragma unroll
      for (int j = 0; j < 8; ++j) {
        float raw = mu8[j] + e8[j] * sg8[j];
        raw = fminf(fmaxf(raw, 0.f), 1.f);
        float thr = 0.f;
#pragma unroll
        for (int jj = 0; jj < 16; ++jj)
          thr = fmaf(thv[jj], wt_s[(c + j) * 17 + jj], thr);
        z8[j] = fmaxf(raw - thr, 0.f);
      }
      float* zp = z_out + (size_t)m2 * DZ + col0 + c;
      *(float4*)zp = make_float4(z8[0], z8[1], z8[2], z8[3]);
      *(float4*)(zp + 4) = make_float4(z8[4], z8[5], z8[6], z8[7]);
      u16x8 zb;
#pragma unroll
      for (int j = 0; j < 8; ++j) zb[j] = f2bf(z8[j]);
      *(u16x8*)(z_bf + (size_t)m2 * DZ + col0 + c) = zb;
      const float* zhp = zhat + (size_t)m2 * DZ + col0 + c;
      float4 h0 = ((const float4*)zhp)[0], h1 = ((const float4*)zhp)[1];
      float zh8[8] = {h0.x, h0.y, h0.z, h0.w, h1.x, h1.y, h1.z, h1.w};
#pragma unroll
      for (int j = 0; j < 8; ++j) {
        float d = z8[j] - zh8[j];
        tsum += d * d;
        esum += z8[j];
      }
    }
  }
  float t = block_sum512(tsum, rbuf);
  if (tid == 0) atomicAdd(scal + 1, t * (1.f / ((float)BB * DZ)));
  float e = block_sum512(esum, rbuf);
  if (tid == 0) atomicAdd(scal + 2, e * (1.f / ((float)BB * DZ)));
}

// ---------------------------------------------------------------------------
// k_rec1: 256 blocks (1/CU), 512 threads (8 waves), 128 rows x 64 cols;
// wave = 16 rows.  A = z_bf direct global->VGPR.  B = 2 x 16 KB Wr1 K=128
// panels.  2 phases, 3 barriers total.
// ---------------------------------------------------------------------------
__global__ __launch_bounds__(512, 2) void k_rec1(const u16* __restrict__ z_bf,
                                                 const u16* __restrict__ Wr1,
                                                 u16* __restrict__ r1_bf) {
  __shared__ __align__(16) u16 smem[2 * 9216];  // 36 KB: ring + epi scratch
  const int tid = threadIdx.x, lane = tid & 63, w = tid >> 6;  // w: 0..7
  const int frow = lane & 15, fq = lane >> 4;
  int row0, col0;
  {
    int xcd = blockIdx.x & 7, t = blockIdx.x >> 3;
    col0 = (t & 3) * 64;
    row0 = ((t >> 2) * 8 + xcd) * 128;
  }
  u16* b0 = smem;
  u16* b1 = smem + 9216;

  f32x4 acc[4];
#pragma unroll
  for (int n = 0; n < 4; ++n) acc[n] = fzero();

  const u16* Abase = z_bf + (size_t)(row0 + w * 16 + frow) * DZ;
  bf16x8 arA[4], arB[4];

  // phase 0 (K 0..127) into b0
  stg64x128(b0, Wr1, col0, DZ, 0);
  lda4(arA, Abase, 0, fq);
  __syncthreads();
  // phase 0 computes b0; prefetch phase 1 (K 128..255) into b1
  stg64x128(b1, Wr1, col0, DZ, 128);
  lda4(arB, Abase, 128, fq);
  hpCmp1(b0, arA, acc, frow, fq);
  __syncthreads();
  hpCmp1(b1, arB, acc, frow, fq);
  __syncthreads();  // all b1 reads done -> scratch reuse

  float* rt = (float*)smem;  // 128 x 66 floats (33792 B <= 36 KB)
#pragma unroll
  for (int n = 0; n < 4; ++n)
#pragma unroll
    for (int r = 0; r < 4; ++r) {
      int lr = w * 16 + fq * 4 + r;
      int ln = n * 16 + frow;
      rt[lr * 66 + ln] = acc[n][r];
    }
  __syncthreads();
  {
    int lr2 = tid >> 2, c0 = (tid & 3) * 16;
    int m2 = row0 + lr2;
    u16* dst = r1_bf + (size_t)m2 * DREC + col0 + c0;
#pragma unroll
    for (int gb = 0; gb < 2; ++gb) {
      u16x8 rb;
#pragma unroll
      for (int j = 0; j < 8; ++j) rb[j] = f2bf(rt[lr2 * 66 + c0 + gb * 8 + j]);
      *(u16x8*)(dst + gb * 8) = rb;
    }
  }
}

// ---------------------------------------------------------------------------
// k_rec2: 1024 blocks, 512 threads (8 waves), 128 rows x 64 cols; wave = 16
// rows.  A = r1_bf direct global->VGPR.  B = 2 x 16 KB Wr2 K=128 panels.
// 2 phases; sigmoid + fused spatial loss.
// ---------------------------------------------------------------------------
__global__ __launch_bounds__(512, 2) void k_rec2(const u16* __restrict__ r1_bf,
                                                 const u16* __restrict__ Wr2,
                                                 const float* __restrict__ I_t,
                                                 float* __restrict__ ihat_out,
                                                 float* __restrict__ scal) {
  __shared__ __align__(16) u16 smem[2 * 9216];  // 36 KB: ring + epi scratch
  __shared__ float rbuf[8];
  const int tid = threadIdx.x, lane = tid & 63, w = tid >> 6;  // w: 0..7
  const int frow = lane & 15, fq = lane >> 4;
  int row0, col0;
  {
    int xcd = blockIdx.x & 7, t = blockIdx.x >> 3;  // t: 0..127
    col0 = (t & 15) * 64;
    row0 = ((t >> 4) * 8 + xcd) * 128;
  }
  u16* b0 = smem;
  u16* b1 = smem + 9216;

  f32x4 acc[4];
#pragma unroll
  for (int n = 0; n < 4; ++n) acc[n] = fzero();

  const u16* Abase = r1_bf + (size_t)(row0 + w * 16 + frow) * DREC;
  bf16x8 arA[4], arB[4];

  // phase 0 (K 0..127) into b0
  stg64x128(b0, Wr2, col0, DREC, 0);
  lda4(arA, Abase, 0, fq);
  __syncthreads();
  // phase 0 computes b0; prefetch phase 1 (K 128..255) into b1
  stg64x128(b1, Wr2, col0, DREC, 128);
  lda4(arB, Abase, 128, fq);
  hpCmp1(b0, arA, acc, frow, fq);
  __syncthreads();
  hpCmp1(b1, arB, acc, frow, fq);
  __syncthreads();  // all b1 reads done -> scratch reuse

  float* it = (float*)smem;  // 128 x 66 floats
#pragma unroll
  for (int n = 0; n < 4; ++n)
#pragma unroll
    for (int r = 0; r < 4; ++r) {
      int lr = w * 16 + fq * 4 + r;
      int ln = n * 16 + frow;
      it[lr * 66 + ln] = 1.f / (1.f + expf(-acc[n][r]));
    }
  __syncthreads();
  float lsum = 0.f;
  {
    int lr2 = tid >> 2, c0 = (tid & 3) * 16;
    int m2 = row0 + lr2;
    float* op = ihat_out + (size_t)m2 * DIN + col0 + c0;
    const float* ip = I_t + (size_t)m2 * DIN + col0 + c0;
#pragma unroll
    for (int gb = 0; gb < 2; ++gb) {
      float i8[8];
#pragma unroll
      for (int j = 0; j < 8; ++j) i8[j] = it[lr2 * 66 + c0 + gb * 8 + j];
      *(float4*)(op + gb * 8) = make_float4(i8[0], i8[1], i8[2], i8[3]);
      *(float4*)(op + gb * 8 + 4) = make_float4(i8[4], i8[5], i8[6], i8[7]);
      float4 a0 = ((const float4*)(ip + gb * 8))[0];
      float4 a1 = ((const float4*)(ip + gb * 8))[1];
      float t8[8] = {a0.x, a0.y, a0.z, a0.w, a1.x, a1.y, a1.z, a1.w};
#pragma unroll
      for (int j = 0; j < 8; ++j) {
        float d = t8[j] - i8[j];
        lsum += d * d;
      }
    }
  }
  float s = block_sum512(lsum, rbuf);
  if (tid == 0) atomicAdd(scal + 0, s * (1.f / ((float)BB * DIN)));
}

// ---------------------------------------------------------------------------
extern "C" void kernel_launch(void* const* d_in, const int* in_sizes, int n_in,
                              void* d_out, int out_size, void* d_ws,
                              size_t ws_size, hipStream_t stream) {
  const float* I_t       = (const float*)d_in[0];
  const float* h_m_1     = (const float*)d_in[1];
  const float* z_m_1     = (const float*)d_in[2];
  const float* theta_m_1 = (const float*)d_in[3];
  const float* eps_z     = (const float*)d_in[4];
  const float* eps_zhat  = (const float*)d_in[5];
  const float* W_post_mu = (const float*)d_in[6];
  const float* W_post_lv = (const float*)d_in[7];
  const float* W_z2h     = (const float*)d_in[8];
  const float* W_h2h     = (const float*)d_in[9];
  const float* W_prior_mu= (const float*)d_in[10];
  const float* W_prior_lv= (const float*)d_in[11];
  const float* W_i2t     = (const float*)d_in[12];
  const float* W_vip2t   = (const float*)d_in[13];
  const float* W_t2z     = (const float*)d_in[14];
  const float* W_rec1    = (const float*)d_in[15];
  const float* W_rec2    = (const float*)d_in[16];

  float* out = (float*)d_out;
  float* ihat = out + OFF_IHAT;
  float* zout = out + OFF_Z;
  float* hout = out + OFF_H;
  float* zhat = out + OFF_ZHAT;
  float* scal = out + OFF_SCAL;

  u16* ws_u = (u16*)d_ws;
  u16* sigma_bf = ws_u + WS_SIGMA;
  u16* z_bf = ws_u + WS_ZBF;
  u16* r1_bf = ws_u + WS_R1BF;

  hipMemsetAsync(scal, 0, 3 * sizeof(float), stream);

  k_cvt<<<555, 256, 0, stream>>>(W_post_mu, W_post_lv, W_z2h, W_h2h,
                                 W_prior_mu, W_prior_lv, W_i2t, W_vip2t,
                                 W_rec1, W_rec2, ws_u + W_PM);

  k_hp<<<256, 512, 0, stream>>>(h_m_1, z_m_1, ws_u + W_H2H, ws_u + W_PRM,
                                ws_u + W_PRL, ws_u + W_Z2H, eps_zhat, hout,
                                zhat, sigma_bf);
  k_post<<<256, 512, 0, stream>>>(I_t, ws_u + W_PM, ws_u + W_PL,
                                  ws_u + W_I2T, ws_u + W_VIP, sigma_bf,
                                  theta_m_1, W_t2z, eps_z, zhat, zout, z_bf,
                                  scal);
  k_rec1<<<256, 512, 0, stream>>>(z_bf, ws_u + W_R1, r1_bf);
  k_rec2<<<1024, 512, 0, stream>>>(r1_bf, ws_u + W_R2, I_t, ihat, scal);
}

// Round 10
// 228.147 us; speedup vs baseline: 1.0007x; 1.0007x over previous
//
#include <hip/hip_runtime.h>
#include <math.h>

#define BB 8192
#define DIN 1024
#define DZ 256
#define DH 256
#define DT 16
#define DREC 256

// d_out layout (floats): I_hat, z, h, z_hat, spatial, temporal, energy
#define OFF_IHAT 0
#define OFF_Z    (BB * DIN)
#define OFF_H    (OFF_Z + BB * DZ)
#define OFF_ZHAT (OFF_H + BB * DH)
#define OFF_SCAL (OFF_ZHAT + BB * DZ)

// ---- workspace layout (u16 element offsets) -------------------------------
#define WS_HBF   0
#define WS_ZM1   2097152
#define WS_W     4194304
#define W_PM  (WS_W + 0)
#define W_PL  (W_PM + 262144)
#define W_Z2H (W_PL + 262144)
#define W_H2H (W_Z2H + 65536)
#define W_PRM (W_H2H + 65536)
#define W_PRL (W_PRM + 65536)
#define W_I2T (W_PRL + 65536)      // pre-scaled by 0.1
#define W_VIP (W_I2T + 16384)      // stored as -relu(W)
#define W_R1  (W_VIP + 4096)
#define W_R2  (W_R1 + 65536)
#define WS_ENDW  (W_R2 + 262144)
#define WS_SIGMA WS_ENDW
#define WS_ZBF   (WS_SIGMA + 2097152)
#define WS_R1BF  (WS_ZBF + 2097152)

typedef unsigned short u16;
typedef __attribute__((ext_vector_type(8))) unsigned short u16x8;
typedef __attribute__((ext_vector_type(8))) __bf16 bf16x8;
typedef __attribute__((ext_vector_type(4))) float f32x4;

#define MFMA __builtin_amdgcn_mfma_f32_16x16x32_bf16

__device__ inline u16 f2bf(float f) {
  unsigned u = __builtin_bit_cast(unsigned, f);
  u += 0x7fff + ((u >> 16) & 1);
  return (u16)(u >> 16);
}
__device__ inline float softplus_stable(float y) {  // log(1+e^y)
  return (y > 20.f) ? y : log1pf(expf(y));
}
__device__ inline bf16x8 gf(const u16* p) {
  return __builtin_bit_cast(bf16x8, *(const u16x8*)p);
}
__device__ inline f32x4 fzero() { return (f32x4){0.f, 0.f, 0.f, 0.f}; }

__device__ inline float block_sum512(float v, float* rbuf) {
#pragma unroll
  for (int off = 32; off > 0; off >>= 1) v += __shfl_down(v, off, 64);
  __syncthreads();
  if ((threadIdx.x & 63) == 0) rbuf[threadIdx.x >> 6] = v;
  __syncthreads();
  float s = 0.f;
#pragma unroll
  for (int i = 0; i < 8; ++i) s += rbuf[i];
  return s;
}

// 128-k-wide panels (512 threads / 8 waves): row = 128 u16 = 256 B;
// one global_load_lds instr covers 4 rows (64 lanes x 16 B).
// LDS[r][c] = G[r][c ^ (r&7)] (chunk involution, c in 0..15) -> conflict-light.
__device__ inline void stg64x128(u16* tile, const u16* __restrict__ g,
                                 int row0, int ldk, int k0) {
  const int lane = threadIdx.x & 63, w = threadIdx.x >> 6;
#pragma unroll
  for (int i = 0; i < 2; ++i) {
    int rb = (w * 2 + i) * 4;              // 8 waves x 2 x 4 rows = 64
    int r = rb + (lane >> 4);
    int d = lane & 15;
    int s = d ^ (r & 7);
    const u16* src = g + (size_t)(row0 + r) * ldk + k0 + s * 8;
    u16* dst = tile + rb * 128;
    __builtin_amdgcn_global_load_lds(
        (const __attribute__((address_space(1))) unsigned int*)(const void*)src,
        (__attribute__((address_space(3))) unsigned int*)(void*)dst, 16, 0, 0);
  }
}
__device__ inline void stg16x128(u16* tile, const u16* __restrict__ g,
                                 int ldk, int k0) {
  const int lane = threadIdx.x & 63, w = threadIdx.x >> 6;
  if (w < 4) {
    int rb = w * 4;                        // 4 waves x 4 rows = 16
    int r = rb + (lane >> 4);
    int d = lane & 15;
    int s = d ^ (r & 7);
    const u16* src = g + (size_t)r * ldk + k0 + s * 8;
    u16* dst = tile + rb * 128;
    __builtin_amdgcn_global_load_lds(
        (const __attribute__((address_space(1))) unsigned int*)(const void*)src,
        (__attribute__((address_space(3))) unsigned int*)(void*)dst, 16, 0, 0);
  }
}
__device__ inline bf16x8 rd128(const u16* tile, int r, int j) {
  return gf(tile + r * 128 + ((j ^ (r & 7)) * 8));
}

// per-phase helpers (all static indexing)
// bf16-source A fragments
__device__ inline void lda4(bf16x8 (&ar)[4], const u16* base, int kwin,
                            int fq) {
#pragma unroll
  for (int kk = 0; kk < 4; ++kk) ar[kk] = gf(base + kwin + kk * 32 + fq * 8);
}
// fp32-source A fragments with in-register bf16 conversion (k_hp only;
// measured 2x REGRESSION when used in k_post -- do not re-apply there).
__device__ inline void lda4f(bf16x8 (&ar)[4], const float* __restrict__ base,
                             int kwin, int fq) {
#pragma unroll
  for (int kk = 0; kk < 4; ++kk) {
    const float* p = base + kwin + kk * 32 + fq * 8;
    float4 v0 = ((const float4*)p)[0];
    float4 v1 = ((const float4*)p)[1];
    float vals[8] = {v0.x, v0.y, v0.z, v0.w, v1.x, v1.y, v1.z, v1.w};
    u16x8 o;
#pragma unroll
    for (int j = 0; j < 8; ++j) o[j] = f2bf(vals[j]);
    ar[kk] = __builtin_bit_cast(bf16x8, o);
  }
}
// k_post: mu/sg (4 cols) + theta
__device__ inline void cmpMain(const u16* buf, bf16x8 (&ar)[4], f32x4 (&mu)[4],
                               f32x4 (&sg)[4], f32x4& tt, int frow, int fq) {
#pragma unroll
  for (int kk = 0; kk < 4; ++kk) {
    int j = kk * 4 + fq;
#pragma unroll
    for (int n = 0; n < 4; ++n) {
      mu[n] = MFMA(ar[kk], rd128(buf, n * 16 + frow, j), mu[n], 0, 0, 0);
      sg[n] = MFMA(ar[kk], rd128(buf + 8192, n * 16 + frow, j), sg[n], 0, 0, 0);
    }
    tt = MFMA(ar[kk], rd128(buf + 16384, frow, j), tt, 0, 0, 0);
  }
}
__device__ inline void cmpSig(const u16* buf, bf16x8 (&ar)[4], f32x4& tt,
                              int frow, int fq) {
#pragma unroll
  for (int kk = 0; kk < 4; ++kk)
    tt = MFMA(ar[kk], rd128(buf + 16384, frow, kk * 4 + fq), tt, 0, 0, 0);
}
// k_hp: 3 mats (pass1) / 1 mat (pass2, also used by k_rec1/k_rec2)
__device__ inline void hpCmp3(const u16* buf, bf16x8 (&ar)[4], f32x4 (&ah)[4],
                              f32x4 (&am)[4], f32x4 (&as_)[4], int frow,
                              int fq) {
#pragma unroll
  for (int kk = 0; kk < 4; ++kk) {
    int j = kk * 4 + fq;
#pragma unroll
    for (int n = 0; n < 4; ++n) {
      ah[n]  = MFMA(ar[kk], rd128(buf, n * 16 + frow, j), ah[n], 0, 0, 0);
      am[n]  = MFMA(ar[kk], rd128(buf + 8192, n * 16 + frow, j), am[n], 0, 0, 0);
      as_[n] = MFMA(ar[kk], rd128(buf + 16384, n * 16 + frow, j), as_[n], 0, 0, 0);
    }
  }
}
__device__ inline void hpCmp1(const u16* buf, bf16x8 (&ar)[4], f32x4 (&ah)[4],
                              int frow, int fq) {
#pragma unroll
  for (int kk = 0; kk < 4; ++kk) {
    int j = kk * 4 + fq;
#pragma unroll
    for (int n = 0; n < 4; ++n)
      ah[n] = MFMA(ar[kk], rd128(buf, n * 16 + frow, j), ah[n], 0, 0, 0);
  }
}

// ---------------------------------------------------------------------------
// k_cvt: fp32 -> bf16 for I (A operand of k_post, bf16 path is measured
// faster than fused fp32 loads) + all weights.  h/zm1 stay fused in k_hp.
// ---------------------------------------------------------------------------
__global__ __launch_bounds__(256) void k_cvt(
    const float* __restrict__ I_t, const float* __restrict__ Wpm,
    const float* __restrict__ Wpl, const float* __restrict__ Wz2h,
    const float* __restrict__ Wh2h, const float* __restrict__ Wprm,
    const float* __restrict__ Wprl, const float* __restrict__ Wi2t,
    const float* __restrict__ Wv, const float* __restrict__ Wr1,
    const float* __restrict__ Wr2, u16* __restrict__ dstI,
    u16* __restrict__ dstW) {
  const int SI = 8388608;
  const int T1 = SI + 262144, T2 = SI + 524288, T3 = SI + 589824,
            T4 = SI + 655360, T5 = SI + 720896, T6 = SI + 786432,
            T7 = SI + 802816, T8 = SI + 806912, T9 = SI + 872448,
            T10 = SI + 1134592;
  int nchunk = T10 / 8;
  for (int c = blockIdx.x * 256 + threadIdx.x; c < nchunk;
       c += gridDim.x * 256) {
    int f = c * 8;
    const float* src;
    float scale = 1.f;
    bool nrelu = false;
    u16* dst;
    if (f < SI) {
      src = I_t + f;
      dst = dstI + f;
    } else {
      dst = dstW + (f - SI);
      if (f < T1)       src = Wpm + (f - SI);
      else if (f < T2)  src = Wpl + (f - T1);
      else if (f < T3)  src = Wz2h + (f - T2);
      else if (f < T4)  src = Wh2h + (f - T3);
      else if (f < T5)  src = Wprm + (f - T4);
      else if (f < T6)  src = Wprl + (f - T5);
      else if (f < T7)  { src = Wi2t + (f - T6); scale = 0.1f; }
      else if (f < T8)  { src = Wv + (f - T7);   nrelu = true; }
      else if (f < T9)  src = Wr1 + (f - T8);
      else              src = Wr2 + (f - T9);
    }
    float4 v0 = *(const float4*)(src);
    float4 v1 = *(const float4*)(src + 4);
    float vals[8] = {v0.x, v0.y, v0.z, v0.w, v1.x, v1.y, v1.z, v1.w};
    u16x8 o;
#pragma unroll
    for (int j = 0; j < 8; ++j) {
      float x = vals[j];
      x = nrelu ? -fmaxf(x, 0.f) : x * scale;
      o[j] = f2bf(x);
    }
    *(u16x8*)(dst) = o;
  }
}

// ---------------------------------------------------------------------------
// k_hp: 256 blocks (1/CU), 512 threads (8 waves), 128x64 tile; wave = 16
// rows.  A (h, zm1) = fp32 direct global->VGPR with fused bf16 cvt.
// B = 2 x 48 KB LDS K=128 panels.  4 phases + two-half-pass epilogue.
// ---------------------------------------------------------------------------
__global__ __launch_bounds__(512, 2) void k_hp(
    const float* __restrict__ h_m_1, const float* __restrict__ z_m_1,
    const u16* __restrict__ Wh2h, const u16* __restrict__ Wprm,
    const u16* __restrict__ Wprl, const u16* __restrict__ Wz2h,
    const float* __restrict__ eps_zhat, float* __restrict__ h_out,
    float* __restrict__ zhat_out, u16* __restrict__ sigma_bf) {
  __shared__ __align__(16) u16 smem[2 * 24576];  // 96 KB panel ring
  const int tid = threadIdx.x, lane = tid & 63, w = tid >> 6;  // w: 0..7
  const int frow = lane & 15, fq = lane >> 4;
  int row0, col0;
  {
    int xcd = blockIdx.x & 7, t = blockIdx.x >> 3;
    col0 = (t & 3) * 64;
    row0 = ((t >> 2) * 8 + xcd) * 128;
  }
  u16* b0 = smem;
  u16* b1 = smem + 24576;

  f32x4 ah[4], am[4], as_[4];
#pragma unroll
  for (int n = 0; n < 4; ++n) { ah[n] = fzero(); am[n] = fzero(); as_[n] = fzero(); }

  const float* Ah = h_m_1 + (size_t)(row0 + w * 16 + frow) * DH;
  const float* Az = z_m_1 + (size_t)(row0 + w * 16 + frow) * DZ;
  bf16x8 arA[4], arB[4];

  // prologue: phase 0 (A=h, K 0..127) into b0
  stg64x128(b0, Wh2h, col0, DH, 0);
  stg64x128(b0 + 8192, Wprm, col0, DH, 0);
  stg64x128(b0 + 16384, Wprl, col0, DH, 0);
  lda4f(arA, Ah, 0, fq);
  // phase 0 computes b0; prefetch phase 1 (A=h, K 128..255) into b1
  __syncthreads();
  stg64x128(b1, Wh2h, col0, DH, 128);
  stg64x128(b1 + 8192, Wprm, col0, DH, 128);
  stg64x128(b1 + 16384, Wprl, col0, DH, 128);
  lda4f(arB, Ah, 128, fq);
  hpCmp3(b0, arA, ah, am, as_, frow, fq);
  // phase 1 computes b1; prefetch phase 2 (A=zm1, Wz2h K 0..127) into b0
  __syncthreads();
  stg64x128(b0, Wz2h, col0, DZ, 0);
  lda4f(arA, Az, 0, fq);
  hpCmp3(b1, arB, ah, am, as_, frow, fq);
  // phase 2 computes b0; prefetch phase 3 (Wz2h K 128..255) into b1
  __syncthreads();
  stg64x128(b1, Wz2h, col0, DZ, 128);
  lda4f(arB, Az, 128, fq);
  hpCmp1(b0, arA, ah, frow, fq);
  // phase 3 computes b1
  __syncthreads();
  hpCmp1(b1, arB, ah, frow, fq);

  // epilogue: two 64-row half-passes; scratch overlaid on dead staging LDS
  float* ht = (float*)smem;              // 64 x 66
  float* mt = (float*)(smem + 8448);     // 64 x 66
  float* st = (float*)(smem + 16896);    // 64 x 66
#pragma unroll 1
  for (int p = 0; p < 2; ++p) {
    __syncthreads();  // (p=0: also guards b1 reads done before overwrite)
    if ((w >> 2) == p) {
#pragma unroll
      for (int n = 0; n < 4; ++n)
#pragma unroll
        for (int r = 0; r < 4; ++r) {
          int lrl = (w & 3) * 16 + fq * 4 + r;
          int ln = n * 16 + frow;
          ht[lrl * 66 + ln] = fmaxf(ah[n][r], 0.f);
          mt[lrl * 66 + ln] = fmaxf(am[n][r], 0.f);
          st[lrl * 66 + ln] = softplus_stable(1.2f * as_[n][r]) * (1.f / 1.2f);
        }
    }
    __syncthreads();
    // linear writes: thread -> row tid>>3 (0..63), cols (tid&7)*8..+8
    int lr2 = tid >> 3, c0 = (tid & 7) * 8;
    int m2 = row0 + p * 64 + lr2;
    float h8[8], mu8[8], sg8[8];
#pragma unroll
    for (int j = 0; j < 8; ++j) {
      h8[j] = ht[lr2 * 66 + c0 + j];
      mu8[j] = mt[lr2 * 66 + c0 + j];
      sg8[j] = st[lr2 * 66 + c0 + j];
    }
    float* hp = h_out + (size_t)m2 * DH + col0 + c0;
    *(float4*)hp = make_float4(h8[0], h8[1], h8[2], h8[3]);
    *(float4*)(hp + 4) = make_float4(h8[4], h8[5], h8[6], h8[7]);
    const float* ep = eps_zhat + (size_t)m2 * DZ + col0 + c0;
    float4 e0 = ((const float4*)ep)[0], e1 = ((const float4*)ep)[1];
    float e8[8] = {e0.x, e0.y, e0.z, e0.w, e1.x, e1.y, e1.z, e1.w};
    float zh8[8];
    u16x8 sb;
#pragma unroll
    for (int j = 0; j < 8; ++j) {
      zh8[j] = mu8[j] + e8[j] * sg8[j];
      sb[j] = f2bf(sg8[j]);
    }
    float* zp = zhat_out + (size_t)m2 * DZ + col0 + c0;
    *(float4*)zp = make_float4(zh8[0], zh8[1], zh8[2], zh8[3]);
    *(float4*)(zp + 4) = make_float4(zh8[4], zh8[5], zh8[6], zh8[7]);
    *(u16x8*)(sigma_bf + (size_t)m2 * DZ + col0 + c0) = sb;
  }
}

// ---------------------------------------------------------------------------
// k_post (R5-proven structure, bf16 A-path RESTORED): 256 blocks (1/CU),
// 512 threads (8 waves), 128 rows x 64 cols; wave = 16 rows x 64 cols.
// A = bf16 I_bf direct global->VGPR (ping-pong arA/arB).  B = 2 x 36 KB
// LDS K=128 panels (Wpm|Wpl|Wi2t), 10-phase ring, ONE __syncthreads/phase.
// ---------------------------------------------------------------------------
__global__ __launch_bounds__(512, 2) void k_post(
    const u16* __restrict__ I_bf, const u16* __restrict__ Wpm,
    const u16* __restrict__ Wpl, const u16* __restrict__ Wi2t,
    const u16* __restrict__ Wv, const u16* __restrict__ sigma_bf,
    const float* __restrict__ theta_m_1, const float* __restrict__ W_t2z,
    const float* __restrict__ eps_z, const float* __restrict__ zhat,
    float* __restrict__ z_out, u16* __restrict__ z_bf,
    float* __restrict__ scal) {
  __shared__ __align__(16) u16 smem[2 * 18432];      // 72 KB panel ring
  __shared__ float thwt[128 * 17 + 64 * 17];         // th_s | wt_s
  __shared__ float rbuf[8];
  const int tid = threadIdx.x, lane = tid & 63, w = tid >> 6;  // w: 0..7
  const int frow = lane & 15, fq = lane >> 4;
  int row0, col0;
  {
    int xcd = blockIdx.x & 7, t = blockIdx.x >> 3;
    col0 = (t & 3) * 64;
    row0 = ((t >> 2) * 8 + xcd) * 128;
  }
  u16* b0 = smem;
  u16* b1 = smem + 18432;

  f32x4 mu[4], sg[4], tt = fzero();
#pragma unroll
  for (int i = 0; i < 4; ++i) { mu[i] = fzero(); sg[i] = fzero(); }

  const u16* Abase = I_bf + (size_t)(row0 + w * 16 + frow) * DIN;
  const u16* Sbase = sigma_bf + (size_t)(row0 + w * 16 + frow) * DZ;
  bf16x8 arA[4], arB[4];

#define STGM(buf, k0)                           \
  stg64x128(buf, Wpm, col0, DIN, k0);           \
  stg64x128((buf) + 8192, Wpl, col0, DIN, k0);  \
  stg16x128((buf) + 16384, Wi2t, DIN, k0)

  // prologue: phase 0 into b0
  STGM(b0, 0);
  lda4(arA, Abase, 0, fq);
  // phases 0..7: main GEMMs (K=1024); phase t computes b[t&1]
  __syncthreads(); STGM(b1, 128); lda4(arB, Abase, 128, fq);
  cmpMain(b0, arA, mu, sg, tt, frow, fq);
  __syncthreads(); STGM(b0, 256); lda4(arA, Abase, 256, fq);
  cmpMain(b1, arB, mu, sg, tt, frow, fq);
  __syncthreads(); STGM(b1, 384); lda4(arB, Abase, 384, fq);
  cmpMain(b0, arA, mu, sg, tt, frow, fq);
  __syncthreads(); STGM(b0, 512); lda4(arA, Abase, 512, fq);
  cmpMain(b1, arB, mu, sg, tt, frow, fq);
  __syncthreads(); STGM(b1, 640); lda4(arB, Abase, 640, fq);
  cmpMain(b0, arA, mu, sg, tt, frow, fq);
  __syncthreads(); STGM(b0, 768); lda4(arA, Abase, 768, fq);
  cmpMain(b1, arB, mu, sg, tt, frow, fq);
  __syncthreads(); STGM(b1, 896); lda4(arB, Abase, 896, fq);
  cmpMain(b0, arA, mu, sg, tt, frow, fq);
  // phase 7 computes b1; prefetch sigma phase 8 (Wv k0=0 into b0.Bt)
  __syncthreads(); stg16x128(b0 + 16384, Wv, DZ, 0); lda4(arA, Sbase, 0, fq);
  cmpMain(b1, arB, mu, sg, tt, frow, fq);
  // phase 8: sigma K 0..127 from b0; prefetch Wv k0=128 into b1.Bt
  __syncthreads(); stg16x128(b1 + 16384, Wv, DZ, 128); lda4(arB, Sbase, 128, fq);
  cmpSig(b0, arA, tt, frow, fq);
  // phase 9: sigma K 128..255 from b1
  __syncthreads();
  cmpSig(b1, arB, tt, frow, fq);
#undef STGM

  __syncthreads();  // staging LDS now dead -> epilogue scratch
  float* mt   = (float*)smem;            // 128 x 66
  float* st   = (float*)(smem + 16896);  // 128 x 66
  float* th_s = thwt;                    // 128 x 17
  float* wt_s = thwt + 128 * 17;         // 64 x 17

  // theta finalize: each wave owns its 16 rows (no in-block redundancy)
#pragma unroll
  for (int r = 0; r < 4; ++r) {
    int lr = w * 16 + fq * 4 + r;
    float th = 0.5f * theta_m_1[(size_t)(row0 + lr) * DT + frow] + tt[r];
    th_s[lr * 17 + frow] = 0.002f * softplus_stable(0.5f * th);
  }
  for (int idx = tid; idx < 64 * 16; idx += 512) {
    int n = idx >> 4, j = idx & 15;
    wt_s[n * 17 + j] = 10.f * fmaxf(W_t2z[(col0 + n) * DT + j], 0.f);
  }
  // scattered mu/sig -> LDS tiles
#pragma unroll
  for (int n = 0; n < 4; ++n)
#pragma unroll
    for (int r = 0; r < 4; ++r) {
      int lr = w * 16 + fq * 4 + r;
      int ln = n * 16 + frow;
      mt[lr * 66 + ln] = fmaxf(mu[n][r], 0.f);
      st[lr * 66 + ln] = fmaxf(sg[n][r], 0.f);
    }
  __syncthreads();
  // linear phase: thread -> row tid>>2, cols (tid&3)*16..+16; z + losses
  float tsum = 0.f, esum = 0.f;
  {
    int lr2 = tid >> 2, c0 = (tid & 3) * 16;
    int m2 = row0 + lr2;
    float thv[16];
#pragma unroll
    for (int j = 0; j < 16; ++j) thv[j] = th_s[lr2 * 17 + j];
#pragma unroll
    for (int gb = 0; gb < 2; ++gb) {
      int c = c0 + gb * 8;
      float mu8[8], sg8[8];
#pragma unroll
      for (int j = 0; j < 8; ++j) {
        mu8[j] = mt[lr2 * 66 + c + j];
        sg8[j] = st[lr2 * 66 + c + j];
      }
      const float* ep = eps_z + (size_t)m2 * DZ + col0 + c;
      float4 e0 = ((const float4*)ep)[0], e1 = ((const float4*)ep)[1];
      float e8[8] = {e0.x, e0.y, e0.z, e0.w, e1.x, e1.y, e1.z, e1.w};
      float z8[8];
#pragma unroll
      for (int j = 0; j < 8; ++j) {
        float raw = mu8[j] + e8[j] * sg8[j];
        raw = fminf(fmaxf(raw, 0.f), 1.f);
        float thr = 0.f;
#pragma unroll
        for (int jj = 0; jj < 16; ++jj)
          thr = fmaf(thv[jj], wt_s[(c + j) * 17 + jj], thr);
        z8[j] = fmaxf(raw - thr, 0.f);
      }
      float* zp = z_out + (size_t)m2 * DZ + col0 + c;
      *(float4*)zp = make_float4(z8[0], z8[1], z8[2], z8[3]);
      *(float4*)(zp + 4) = make_float4(z8[4], z8[5], z8[6], z8[7]);
      u16x8 zb;
#pragma unroll
      for (int j = 0; j < 8; ++j) zb[j] = f2bf(z8[j]);
      *(u16x8*)(z_bf + (size_t)m2 * DZ + col0 + c) = zb;
      const float* zhp = zhat + (size_t)m2 * DZ + col0 + c;
      float4 h0 = ((const float4*)zhp)[0], h1 = ((const float4*)zhp)[1];
      float zh8[8] = {h0.x, h0.y, h0.z, h0.w, h1.x, h1.y, h1.z, h1.w};
#pragma unroll
      for (int j = 0; j < 8; ++j) {
        float d = z8[j] - zh8[j];
        tsum += d * d;
        esum += z8[j];
      }
    }
  }
  float t = block_sum512(tsum, rbuf);
  if (tid == 0) atomicAdd(scal + 1, t * (1.f / ((float)BB * DZ)));
  float e = block_sum512(esum, rbuf);
  if (tid == 0) atomicAdd(scal + 2, e * (1.f / ((float)BB * DZ)));
}

// ---------------------------------------------------------------------------
// k_rec1: 256 blocks (1/CU), 512 threads (8 waves), 128 rows x 64 cols;
// wave = 16 rows.  A = z_bf direct global->VGPR.  B = 2 x 16 KB Wr1 K=128
// panels.  2 phases, 3 barriers total.
// ---------------------------------------------------------------------------
__global__ __launch_bounds__(512, 2) void k_rec1(const u16* __restrict__ z_bf,
                                                 const u16* __restrict__ Wr1,
                                                 u16* __restrict__ r1_bf) {
  __shared__ __align__(16) u16 smem[2 * 9216];  // 36 KB: ring + epi scratch
  const int tid = threadIdx.x, lane = tid & 63, w = tid >> 6;  // w: 0..7
  const int frow = lane & 15, fq = lane >> 4;
  int row0, col0;
  {
    int xcd = blockIdx.x & 7, t = blockIdx.x >> 3;
    col0 = (t & 3) * 64;
    row0 = ((t >> 2) * 8 + xcd) * 128;
  }
  u16* b0 = smem;
  u16* b1 = smem + 9216;

  f32x4 acc[4];
#pragma unroll
  for (int n = 0; n < 4; ++n) acc[n] = fzero();

  const u16* Abase = z_bf + (size_t)(row0 + w * 16 + frow) * DZ;
  bf16x8 arA[4], arB[4];

  // phase 0 (K 0..127) into b0
  stg64x128(b0, Wr1, col0, DZ, 0);
  lda4(arA, Abase, 0, fq);
  __syncthreads();
  // phase 0 computes b0; prefetch phase 1 (K 128..255) into b1
  stg64x128(b1, Wr1, col0, DZ, 128);
  lda4(arB, Abase, 128, fq);
  hpCmp1(b0, arA, acc, frow, fq);
  __syncthreads();
  hpCmp1(b1, arB, acc, frow, fq);
  __syncthreads();  // all b1 reads done -> scratch reuse

  float* rt = (float*)smem;  // 128 x 66 floats (33792 B <= 36 KB)
#pragma unroll
  for (int n = 0; n < 4; ++n)
#pragma unroll
    for (int r = 0; r < 4; ++r) {
      int lr = w * 16 + fq * 4 + r;
      int ln = n * 16 + frow;
      rt[lr * 66 + ln] = acc[n][r];
    }
  __syncthreads();
  {
    int lr2 = tid >> 2, c0 = (tid & 3) * 16;
    int m2 = row0 + lr2;
    u16* dst = r1_bf + (size_t)m2 * DREC + col0 + c0;
#pragma unroll
    for (int gb = 0; gb < 2; ++gb) {
      u16x8 rb;
#pragma unroll
      for (int j = 0; j < 8; ++j) rb[j] = f2bf(rt[lr2 * 66 + c0 + gb * 8 + j]);
      *(u16x8*)(dst + gb * 8) = rb;
    }
  }
}

// ---------------------------------------------------------------------------
// k_rec2: 1024 blocks, 512 threads (8 waves), 128 rows x 64 cols; wave = 16
// rows.  A = r1_bf direct global->VGPR.  B = 2 x 16 KB Wr2 K=128 panels.
// 2 phases; sigmoid + fused spatial loss.
// ---------------------------------------------------------------------------
__global__ __launch_bounds__(512, 2) void k_rec2(const u16* __restrict__ r1_bf,
                                                 const u16* __restrict__ Wr2,
                                                 const float* __restrict__ I_t,
                                                 float* __restrict__ ihat_out,
                                                 float* __restrict__ scal) {
  __shared__ __align__(16) u16 smem[2 * 9216];  // 36 KB: ring + epi scratch
  __shared__ float rbuf[8];
  const int tid = threadIdx.x, lane = tid & 63, w = tid >> 6;  // w: 0..7
  const int frow = lane & 15, fq = lane >> 4;
  int row0, col0;
  {
    int xcd = blockIdx.x & 7, t = blockIdx.x >> 3;  // t: 0..127
    col0 = (t & 15) * 64;
    row0 = ((t >> 4) * 8 + xcd) * 128;
  }
  u16* b0 = smem;
  u16* b1 = smem + 9216;

  f32x4 acc[4];
#pragma unroll
  for (int n = 0; n < 4; ++n) acc[n] = fzero();

  const u16* Abase = r1_bf + (size_t)(row0 + w * 16 + frow) * DREC;
  bf16x8 arA[4], arB[4];

  // phase 0 (K 0..127) into b0
  stg64x128(b0, Wr2, col0, DREC, 0);
  lda4(arA, Abase, 0, fq);
  __syncthreads();
  // phase 0 computes b0; prefetch phase 1 (K 128..255) into b1
  stg64x128(b1, Wr2, col0, DREC, 128);
  lda4(arB, Abase, 128, fq);
  hpCmp1(b0, arA, acc, frow, fq);
  __syncthreads();
  hpCmp1(b1, arB, acc, frow, fq);
  __syncthreads();  // all b1 reads done -> scratch reuse

  float* it = (float*)smem;  // 128 x 66 floats
#pragma unroll
  for (int n = 0; n < 4; ++n)
#pragma unroll
    for (int r = 0; r < 4; ++r) {
      int lr = w * 16 + fq * 4 + r;
      int ln = n * 16 + frow;
      it[lr * 66 + ln] = 1.f / (1.f + expf(-acc[n][r]));
    }
  __syncthreads();
  float lsum = 0.f;
  {
    int lr2 = tid >> 2, c0 = (tid & 3) * 16;
    int m2 = row0 + lr2;
    float* op = ihat_out + (size_t)m2 * DIN + col0 + c0;
    const float* ip = I_t + (size_t)m2 * DIN + col0 + c0;
#pragma unroll
    for (int gb = 0; gb < 2; ++gb) {
      float i8[8];
#pragma unroll
      for (int j = 0; j < 8; ++j) i8[j] = it[lr2 * 66 + c0 + gb * 8 + j];
      *(float4*)(op + gb * 8) = make_float4(i8[0], i8[1], i8[2], i8[3]);
      *(float4*)(op + gb * 8 + 4) = make_float4(i8[4], i8[5], i8[6], i8[7]);
      float4 a0 = ((const float4*)(ip + gb * 8))[0];
      float4 a1 = ((const float4*)(ip + gb * 8))[1];
      float t8[8] = {a0.x, a0.y, a0.z, a0.w, a1.x, a1.y, a1.z, a1.w};
#pragma unroll
      for (int j = 0; j < 8; ++j) {
        float d = t8[j] - i8[j];
        lsum += d * d;
      }
    }
  }
  float s = block_sum512(lsum, rbuf);
  if (tid == 0) atomicAdd(scal + 0, s * (1.f / ((float)BB * DIN)));
}

// ---------------------------------------------------------------------------
extern "C" void kernel_launch(void* const* d_in, const int* in_sizes, int n_in,
                              void* d_out, int out_size, void* d_ws,
                              size_t ws_size, hipStream_t stream) {
  const float* I_t       = (const float*)d_in[0];
  const float* h_m_1     = (const float*)d_in[1];
  const float* z_m_1     = (const float*)d_in[2];
  const float* theta_m_1 = (const float*)d_in[3];
  const float* eps_z     = (const float*)d_in[4];
  const float* eps_zhat  = (const float*)d_in[5];
  const float* W_post_mu = (const float*)d_in[6];
  const float* W_post_lv = (const float*)d_in[7];
  const float* W_z2h     = (const float*)d_in[8];
  const float* W_h2h     = (const float*)d_in[9];
  const float* W_prior_mu= (const float*)d_in[10];
  const float* W_prior_lv= (const float*)d_in[11];
  const float* W_i2t     = (const float*)d_in[12];
  const float* W_vip2t   = (const float*)d_in[13];
  const float* W_t2z     = (const float*)d_in[14];
  const float* W_rec1    = (const float*)d_in[15];
  const float* W_rec2    = (const float*)d_in[16];

  float* out = (float*)d_out;
  float* ihat = out + OFF_IHAT;
  float* zout = out + OFF_Z;
  float* hout = out + OFF_H;
  float* zhat = out + OFF_ZHAT;
  float* scal = out + OFF_SCAL;

  u16* ws_u = (u16*)d_ws;
  u16* I_bf = (u16*)ihat;  // scratch inside d_out, dead before k_rec2 writes
  u16* sigma_bf = ws_u + WS_SIGMA;
  u16* z_bf = ws_u + WS_ZBF;
  u16* r1_bf = ws_u + WS_R1BF;

  hipMemsetAsync(scal, 0, 3 * sizeof(float), stream);

  k_cvt<<<2048, 256, 0, stream>>>(I_t, W_post_mu, W_post_lv, W_z2h, W_h2h,
                                  W_prior_mu, W_prior_lv, W_i2t, W_vip2t,
                                  W_rec1, W_rec2, I_bf, ws_u + W_PM);

  k_hp<<<256, 512, 0, stream>>>(h_m_1, z_m_1, ws_u + W_H2H, ws_u + W_PRM,
                                ws_u + W_PRL, ws_u + W_Z2H, eps_zhat, hout,
                                zhat, sigma_bf);
  k_post<<<256, 512, 0, stream>>>(I_bf, ws_u + W_PM, ws_u + W_PL,
                                  ws_u + W_I2T, ws_u + W_VIP, sigma_bf,
                                  theta_m_1, W_t2z, eps_z, zhat, zout, z_bf,
                                  scal);
  k_rec1<<<256, 512, 0, stream>>>(z_bf, ws_u + W_R1, r1_bf);
  k_rec2<<<1024, 512, 0, stream>>>(r1_bf, ws_u + W_R2, I_t, ihat, scal);
}